// Round 3
// baseline (116.365 us; speedup 1.0000x reference)
//
#include <hip/hip_runtime.h>

// MXIntSoftmax — bit-exact integer port, round 9: R8 (conflict-halved LUTs + nt streaming)
// with the nontemporal builtin applied via a native ext_vector float4 (HIP_vector_type
// is rejected by __builtin_nontemporal_*).
//
// Semantics (verified absmax=0 across R1..R7):
//   yq    = clip(floor(clip(rne(x*2^(7-e)),-128,127) * 46 * 2^(e-7+5)), -256, 255),
//           e = clip(ceil(log2|x|),-8,7)  — exponent-field bit math + f32 (exact)
//   e8    = (yq>>5)+8 in [0,15] ; me = rint(exp2((yq&31)/32+6)) in [64,125]
//   scan  -> single floor: partial += ((me<<4) >> (E8-e8)) << E8, E8 = prefix max of e8
//   msum  = total >> Estar8 in [1024,2^22) ; magic = floor(2^38/msum)+1 (f64, exact)
//   out   = finalLUT[yq+256] — fuses mout=floor(me*256/msum) and mxint quant.
//
// R9 = R6 structure (2 rows/block, 16 elems/thread, 2 waves/row) +
//   * s_pk / s_fin duplicated 2x (copy selected by lane parity; same entry 8 banks apart)
//   * nontemporal float4 loads/stores via ext_vector type (nt bit; pure streaming)

#define D_DIM 2048
#define TPB   256

typedef float vf4 __attribute__((ext_vector_type(4)));   // nontemporal-compatible float4

// byte-wise max of two u32 whose bytes are <= 15
__device__ __forceinline__ unsigned bmax4(unsigned x, unsigned y) {
    const unsigned d     = (x | 0x80808080u) - y;
    const unsigned flags = d & 0x80808080u;
    const unsigned mask  = (flags - (flags >> 7)) | flags;
    return (x & mask) | (y & ~mask);
}

__global__ __launch_bounds__(TPB, 6) void mxint_softmax_kernel(const float* __restrict__ x,
                                                               float* __restrict__ out) {
    const int t    = threadIdx.x;
    const int lane = t & 63;
    const int wid  = t >> 6;           // 4 waves: (0,1)->row0, (2,3)->row1
    const int half = wid & 1;
    const int r    = wid >> 1;
    const int row  = blockIdx.x * 2 + r;

    // 2x replicated tables; copy offset chosen so same entry lands 8 banks apart.
    __shared__ unsigned short     s_pk[2][528];    // me<<4 keyed by yq+256 (static)
    __shared__ float              s_fin[2][2][520];// [row][copy][entry] fused output LUT
    __shared__ int                s_rmax[4];       // per-wave max e8 (biased)
    __shared__ unsigned long long s_part[4];       // per-wave partial sums

    // ---- issue global loads first: thread covers 4 rounds x float4 (nt: streamed) ----
    const size_t base = (size_t)row * D_DIM + half * 1024 + lane * 4;
    vf4 v[4];
#pragma unroll
    for (int i = 0; i < 4; ++i)
        v[i] = __builtin_nontemporal_load((const vf4*)(x + base + i * 256));

    // ---- static pk LUT: 2 entries/thread x 2 copies, overlaps load latency ----
#pragma unroll
    for (int q = 0; q < 2; ++q) {
        const int idx = t + 256 * q;
        const float a = fmaf((float)(idx & 31), 0.03125f, 6.0f);
        const int  me = (int)rintf(__builtin_amdgcn_exp2f(a));   // exact TAB match (17x margin)
        const unsigned short pv = (unsigned short)(me << 4);
        s_pk[0][idx] = pv;
        s_pk[1][idx] = pv;
    }

    // ---- front end: yq per element; per-round maxima packed as bytes ----
    int yq[16];
    unsigned pe = 0;
#pragma unroll
    for (int i = 0; i < 4; ++i) {
        const float xs4[4] = {v[i].x, v[i].y, v[i].z, v[i].w};
        int rmaxr = -256;
#pragma unroll
        for (int k = 0; k < 4; ++k) {
            const unsigned b  = __float_as_uint(xs4[k]) & 0x7fffffffu;
            const unsigned tb = b + 0x7fffffu;
            const unsigned tc = min(max(tb, 0x3B800000u), 0x43000000u);  // clamp exp field
            const unsigned es = tc & 0xFF800000u;                        // ebc<<23
            const float    su  = __uint_as_float(0x82800000u - es);      // 2^(134-ebc)
            const float    fac = __uint_as_float(es + 0xFF380000u);      // 46*2^(ebc-134)
            const float    mi  = __builtin_amdgcn_fmed3f(rintf(xs4[k] * su), -128.0f, 127.0f);
            int y = (int)floorf(mi * fac);                               // exact product
            y = min(255, max(-256, y));
            yq[4 * i + k] = y;
            rmaxr = max(rmaxr, y);
        }
        pe |= (unsigned)((rmaxr >> 5) + 8) << (8 * i);     // biased e8 round-max byte
    }

    // ---- one SWAR wave scan (4 round-bytes at once) ----
    unsigned s = pe;
#pragma unroll
    for (int d = 1; d < 64; d <<= 1) {
        const unsigned o = __shfl_up(s, d, 64);
        if (lane >= d) s = bmax4(s, o);
    }
    unsigned ex = __shfl_up(s, 1, 64);
    if (lane == 0) ex = 0;
    const unsigned bc = __shfl(s, 63, 64);                 // per-round wave totals
    const int wtot = max(max((int)(bc & 255u), (int)((bc >> 8) & 255u)),
                         max((int)((bc >> 16) & 255u), (int)(bc >> 24)));
    s_rmax[wid] = wtot;
    __syncthreads();                                       // B1: pk LUT + wave totals ready

    // carry: second-half wave starts after first half's full max
    const int c0 = half ? s_rmax[wid - 1] : 0;

    // ---- weighted sum (collapsed scan), u32 partial (16 terms < 2^30) ----
    const unsigned short* pk = s_pk[lane & 1];
    unsigned partial = 0;
    int crun = c0;
#pragma unroll
    for (int i = 0; i < 4; ++i) {
        const int sx   = (int)((ex >> (8 * i)) & 255u);
        int a = max(crun, sx);
#pragma unroll
        for (int k = 0; k < 4; ++k) {
            const int y  = yq[4 * i + k];
            const int h  = (y >> 5) + 8;                   // e8 biased [0,15]
            a = max(a, h);                                 // inclusive prefix max
            const unsigned me4 = pk[y + 256];              // me<<4
            partial += (me4 >> (a - h)) << a;              // floor term << (E+8)
        }
        crun = max(crun, (int)((bc >> (8 * i)) & 255u));
    }

    // ---- butterfly reduce within wave (1 u32 step, then u64) ----
    const unsigned ps = partial + __shfl_xor(partial, 1, 64);   // pair < 2^31.1, safe
    unsigned long long p64 = ps;
#pragma unroll
    for (int d = 2; d < 64; d <<= 1) p64 += __shfl_xor(p64, d, 64);
    s_part[wid] = p64;          // every lane has it; benign same-value write
    __syncthreads();            // B2: partials + maxima ready

    const unsigned long long tot = s_part[2 * r] + s_part[2 * r + 1];
    const int      Estar8 = max(s_rmax[2 * r], s_rmax[2 * r + 1]);
    const unsigned msum   = (unsigned)(tot >> Estar8);          // [1024, 2^22)
    const unsigned magic  = (unsigned)(274877906944.0 / (double)msum) + 1u;  // floor(2^38/m)+1

    // ---- per-row fused final LUT: 4 entries x 2 copies per thread (128 thr/row) ----
    const int tr = t & 127;
#pragma unroll
    for (int q = 0; q < 4; ++q) {
        const int      idx  = tr + 128 * q;                // 0..511  (yq = idx-256)
        const unsigned me4  = s_pk[0][idx];
        const unsigned mout = __umulhi(me4 << 4, magic) >> 6;   // floor(me*256/msum), [0,31]
        const int      e8   = idx >> 5;                        // == (yq>>5)+8
        const int      eoutn = Estar8 - e8;                    // [0,15]
        const int      bl   = 32 - __clz((int)(mout | 1u));
        const int      pw2  = ((mout & (mout - 1u)) == 0u) ? 1 : 0;
        const int      clog = bl - pw2;
        const int      sq   = min(7 - clog, 11 - eoutn);
        const int      rs   = 8 - sq;                          // [1,12]
        const unsigned u    = mout << 8;
        const unsigned bse  = u >> rs;
        const unsigned frac = u & ((1u << rs) - 1u);
        const unsigned hlf  = 1u << (rs - 1);
        unsigned m2 = bse + (((frac > hlf) || (frac == hlf && (bse & 1u))) ? 1u : 0u);
        m2 = min(m2, 127u);
        const int ef = max(clog - eoutn - 4, -8);
        const float fv = (float)m2 * __uint_as_float((unsigned)(ef + 120) << 23);
        s_fin[r][0][idx] = fv;
        s_fin[r][1][idx] = fv;
    }
    __syncthreads();            // B3: final LUTs ready

    // ---- epilogue: one LDS read per element, coalesced nt float4 stores ----
    const float* tab = s_fin[r][lane & 1];
    float* orow = out + base;
#pragma unroll
    for (int i = 0; i < 4; ++i) {
        vf4 o4;
#pragma unroll
        for (int k = 0; k < 4; ++k)
            o4[k] = tab[yq[4 * i + k] + 256];
        __builtin_nontemporal_store(o4, (vf4*)(orow + i * 256));
    }
}

extern "C" void kernel_launch(void* const* d_in, const int* in_sizes, int n_in,
                              void* d_out, int out_size, void* d_ws, size_t ws_size,
                              hipStream_t stream) {
    const float* x = (const float*)d_in[0];
    float*       o = (float*)d_out;
    const int rows = in_sizes[0] / D_DIM;      // 8192
    mxint_softmax_kernel<<<rows / 2, TPB, 0, stream>>>(x, o);
}